// Round 4
// baseline (243.868 us; speedup 1.0000x reference)
//
#include <hip/hip_runtime.h>

// DWT db4 depthwise stride-2 decomposition.
// x: [B=32, T=16384, C=64] f32 -> out: [B, T2=8190, 2C=128] f32
// out[b,t,c]    = sum_k lo[k] * x[b, reflect(2t+k-1), c]      (c < 64)
// out[b,t,64+c] = sum_k hi[k] * x[b, reflect(2t+k-1), c]
//
// R4: identical quad structure to R3, ONE variable changed:
// __launch_bounds__(256) -> __launch_bounds__(256, 4).
// R3 post-mortem: compiler allocated VGPR=68 (8-wave occupancy target),
// which cannot hold the 14-float4 window (56) + 8 float4 acc (32) + addr.
// It serialized the loads into load->wait->consume->reuse bursts, making the
// kernel dependency-stall bound (VALUBusy 6.4%, HBM 29%, zero conflicts,
// 88us vs R2's 66us).  (256,4) caps VGPR at 128 -- the 4-waves/SIMD
// occupancy step -- letting all 14 loads stay in flight with one wait,
// at the same 4 waves/SIMD residency the 68-VGPR build actually delivered.
// Expected: VGPR ~110-128, dispatch 88 -> ~55-65us.

#define BT    32
#define TT    16384
#define CC    64
#define T2    8190        // T/2 - 2
#define OC    128         // 2*CC
#define NQUAD 2048        // ceil(T2/4); last quad has only 2 valid outputs

__global__ __launch_bounds__(256, 4) void dwt_db4_quad_kernel(
    const float* __restrict__ x,
    const float* __restrict__ dec_lo,
    const float* __restrict__ dec_hi,
    float* __restrict__ out)
{
    const int tid  = threadIdx.x;
    const int cg   = tid & 15;               // channel group: 4 ch via float4
    const int tq   = tid >> 4;               // 0..15: quad slot within block
    const int quad = blockIdx.x * 16 + tq;   // 0..2047 (grid.x = 128, exact)
    const int b    = blockIdx.y;

    const int t0 = quad * 4;
    const int c4 = cg * 4;
    const int m0 = 2 * t0 - 1;               // first input row of the window

    const float* __restrict__ xb = x + (size_t)b * TT * CC;

    // 14-row window: rows m0 .. m0+13 ; output t0+i (i=0..3) uses w[2i..2i+7].
    // Issued FIRST so the global loads are in flight before anything waits.
    float4 w[14];
    if (m0 >= 0 && m0 + 13 <= TT - 1) {
        // Interior: affine addresses -> one base + immediate offsets.
        const float* __restrict__ p = xb + (size_t)m0 * CC + c4;
        #pragma unroll
        for (int i = 0; i < 14; ++i)
            w[i] = *reinterpret_cast<const float4*>(p + i * CC);
    } else {
        // Boundary (quad 0 / quad 2047 per batch): general reflect path.
        // Tail quad reads up to m=2*8191+6=16388 -> reflects to 16378 (safe);
        // the extra outputs are computed but not stored.
        #pragma unroll
        for (int i = 0; i < 14; ++i) {
            int m  = m0 + i;
            int mm = m < 0 ? -m : m;                          // left reflect
            mm     = mm > (TT - 1) ? 2 * (TT - 1) - mm : mm;  // right reflect
            w[i] = *reinterpret_cast<const float4*>(xb + (size_t)mm * CC + c4);
        }
    }

    // Filters: uniform addresses -> scalar broadcast loads (lgkmcnt path,
    // independent of the vmcnt loads above).
    float flo[8], fhi[8];
    #pragma unroll
    for (int k = 0; k < 8; ++k) { flo[k] = dec_lo[k]; fhi[k] = dec_hi[k]; }

    float4 alo[4], ahi[4];
    #pragma unroll
    for (int i = 0; i < 4; ++i) {
        alo[i].x = alo[i].y = alo[i].z = alo[i].w = 0.0f;
        ahi[i].x = ahi[i].y = ahi[i].z = ahi[i].w = 0.0f;
    }

    // Fully unrolled: every w[]/alo[]/ahi[] index is compile-time constant
    // (runtime-indexed vector arrays would go to scratch).
    #pragma unroll
    for (int k = 0; k < 8; ++k) {
        #pragma unroll
        for (int i = 0; i < 4; ++i) {
            const float4 v = w[2 * i + k];
            alo[i].x = fmaf(flo[k], v.x, alo[i].x);
            alo[i].y = fmaf(flo[k], v.y, alo[i].y);
            alo[i].z = fmaf(flo[k], v.z, alo[i].z);
            alo[i].w = fmaf(flo[k], v.w, alo[i].w);
            ahi[i].x = fmaf(fhi[k], v.x, ahi[i].x);
            ahi[i].y = fmaf(fhi[k], v.y, ahi[i].y);
            ahi[i].z = fmaf(fhi[k], v.z, ahi[i].z);
            ahi[i].w = fmaf(fhi[k], v.w, ahi[i].w);
        }
    }

    // Stores: affine (one base + immediates, max 3*512+256 = 1792 < 4096).
    float* __restrict__ ob = out + (size_t)b * T2 * OC + (size_t)t0 * OC + c4;
    if (t0 + 4 <= T2) {
        #pragma unroll
        for (int i = 0; i < 4; ++i) {
            *reinterpret_cast<float4*>(ob + i * OC)      = alo[i];
            *reinterpret_cast<float4*>(ob + i * OC + CC) = ahi[i];
        }
    } else {
        // Tail quad (t0 = 8188): only t = 8188, 8189 are valid.
        #pragma unroll
        for (int i = 0; i < 4; ++i) {
            if (t0 + i < T2) {
                *reinterpret_cast<float4*>(ob + i * OC)      = alo[i];
                *reinterpret_cast<float4*>(ob + i * OC + CC) = ahi[i];
            }
        }
    }
}

extern "C" void kernel_launch(void* const* d_in, const int* in_sizes, int n_in,
                              void* d_out, int out_size, void* d_ws, size_t ws_size,
                              hipStream_t stream)
{
    const float* x      = (const float*)d_in[0];
    const float* dec_lo = (const float*)d_in[1];
    const float* dec_hi = (const float*)d_in[2];
    float*       out    = (float*)d_out;

    dim3 block(256);
    // 16 quads per block -> 2048/16 = 128 tiles; x 32 batches
    dim3 grid(NQUAD / 16, BT);

    hipLaunchKernelGGL(dwt_db4_quad_kernel, grid, block, 0, stream,
                       x, dec_lo, dec_hi, out);
}

// Round 5
// 234.781 us; speedup vs baseline: 1.0387x; 1.0387x over previous
//
#include <hip/hip_runtime.h>

// DWT db4 depthwise stride-2 decomposition.
// x: [B=32, T=16384, C=64] f32 -> out: [B, T2=8190, 2C=128] f32
// out[b,t,c]    = sum_k lo[k] * x[b, reflect(2t+k-1), c]      (c < 64)
// out[b,t,64+c] = sum_k hi[k] * x[b, reflect(2t+k-1), c]
//
// R5: LDS-staged via __builtin_amdgcn_global_load_lds (m97 pattern).
// R3/R4 post-mortem: register-window batching is compiler-defeated -- hipcc
// minimizes VGPR pressure (60-68 alloc) and serializes the 14-load window
// into load->wait->consume bursts; kernel was latency-bound at 88us with NO
// saturated pipe (VALU 6%, HBM 28%, conflicts 0).  global_load_lds uses zero
// registers, so all 34 staging chunks (1 KB each) issue back-to-back with a
// single vmcnt drain at the barrier: ~136 KB outstanding per CU (4 blocks),
// which is how the 6.6 TB/s fill kernels behave.  Each input byte fetched
// exactly once; window re-reads hit LDS (~235 MB at 69 TB/s = ~5 us).
//
// Block = 64 outputs x 64 ch x 1 batch.  Stage rows 2*t0-1 .. +133 (134 rows,
// 34.8 KB linear LDS -- no swizzle: global_load_lds dest must be linear).
// 4 blocks/CU (LDS-limited) -> stage/compute phases of different blocks
// overlap on the CU.

#define BT     32
#define TT     16384
#define CC     64
#define T2     8190        // T/2 - 2
#define OC     128         // 2*CC
#define TBLK   64          // outputs per block
#define NROWS  136         // staged rows: 134 needed + 2 pad for 1KB chunking
#define NCHUNK 34          // NROWS*256B / 1024B

__global__ __launch_bounds__(256, 4) void dwt_db4_lds_kernel(
    const float* __restrict__ x,
    const float* __restrict__ dec_lo,
    const float* __restrict__ dec_hi,
    float* __restrict__ out)
{
    __shared__ float lds[NROWS * CC];          // 34816 B

    const int tid = threadIdx.x;
    const int b   = blockIdx.y;
    const int t0  = blockIdx.x * TBLK;         // first output of this tile
    // first staged global row (tile 0 starts at row 0; reflect handled on read)
    const int row_base = (t0 == 0) ? 0 : (2 * t0 - 1);

    const float* __restrict__ xb = x + (size_t)b * TT * CC;

    // ---- stage: 34 x 1KB chunks, round-robin over the 4 waves ----------
    // Each global_load_lds moves 64 lanes x 16B = 1KB to LDS base + lane*16.
    // Zero VGPR involvement -> all issued in flight before the barrier wait.
    {
        const int wave = tid >> 6;
        const int lane = tid & 63;
        const float* gsrc = xb + (size_t)row_base * CC + lane * 4;
        const float* gend = xb + (size_t)TT * CC - 4;   // last valid float4
        #pragma unroll
        for (int c = wave; c < NCHUNK; c += 4) {
            const float* g = gsrc + c * 256;            // 256 floats = 1KB
            g = (g > gend) ? gend : g;                  // per-lane clamp (tail tile pad)
            __builtin_amdgcn_global_load_lds(
                (const __attribute__((address_space(1))) unsigned int*)g,
                (__attribute__((address_space(3))) unsigned int*)&lds[c * 256],
                16, 0, 0);
        }
    }

    // Filters: scalar broadcast loads (lgkm path, overlaps staging).
    float flo[8], fhi[8];
    #pragma unroll
    for (int k = 0; k < 8; ++k) { flo[k] = dec_lo[k]; fhi[k] = dec_hi[k]; }

    __syncthreads();   // compiler emits s_waitcnt vmcnt(0) lgkmcnt(0) first

    // ---- compute: quad of outputs per thread, window from LDS -----------
    const int cg = tid & 15;                   // channel group (4 ch, float4)
    const int tq = tid >> 4;                   // 0..15: quad slot
    const int t  = t0 + tq * 4;                // first output of this quad
    const int c4 = cg * 4;

    // 14-row window; output t+i uses lds rows w[2i..2i+7].
    float4 w[14];
    #pragma unroll
    for (int i = 0; i < 14; ++i) {
        int m  = 2 * t - 1 + i;                           // global row wanted
        int mm = m < 0 ? -m : m;                          // left reflect
        mm     = mm > (TT - 1) ? 2 * (TT - 1) - mm : mm;  // right reflect
        int lr = mm - row_base;                           // staged LDS row
        w[i] = *reinterpret_cast<const float4*>(&lds[lr * CC + c4]);
    }

    float4 alo[4], ahi[4];
    #pragma unroll
    for (int i = 0; i < 4; ++i) {
        alo[i].x = alo[i].y = alo[i].z = alo[i].w = 0.0f;
        ahi[i].x = ahi[i].y = ahi[i].z = ahi[i].w = 0.0f;
    }

    #pragma unroll
    for (int k = 0; k < 8; ++k) {
        #pragma unroll
        for (int i = 0; i < 4; ++i) {
            const float4 v = w[2 * i + k];
            alo[i].x = fmaf(flo[k], v.x, alo[i].x);
            alo[i].y = fmaf(flo[k], v.y, alo[i].y);
            alo[i].z = fmaf(flo[k], v.z, alo[i].z);
            alo[i].w = fmaf(flo[k], v.w, alo[i].w);
            ahi[i].x = fmaf(fhi[k], v.x, ahi[i].x);
            ahi[i].y = fmaf(fhi[k], v.y, ahi[i].y);
            ahi[i].z = fmaf(fhi[k], v.z, ahi[i].z);
            ahi[i].w = fmaf(fhi[k], v.w, ahi[i].w);
        }
    }

    // ---- stores: lanes 0-15 contiguous 256B per instruction --------------
    float* __restrict__ ob = out + (size_t)b * T2 * OC + (size_t)t * OC + c4;
    #pragma unroll
    for (int i = 0; i < 4; ++i) {
        if (t + i < T2) {                       // tail tile: t=8188..8191
            *reinterpret_cast<float4*>(ob + i * OC)      = alo[i];
            *reinterpret_cast<float4*>(ob + i * OC + CC) = ahi[i];
        }
    }
}

extern "C" void kernel_launch(void* const* d_in, const int* in_sizes, int n_in,
                              void* d_out, int out_size, void* d_ws, size_t ws_size,
                              hipStream_t stream)
{
    const float* x      = (const float*)d_in[0];
    const float* dec_lo = (const float*)d_in[1];
    const float* dec_hi = (const float*)d_in[2];
    float*       out    = (float*)d_out;

    dim3 block(256);
    // 64 outputs per block -> ceil(8190/64) = 128 tiles; x 32 batches
    dim3 grid((T2 + TBLK - 1) / TBLK, BT);

    hipLaunchKernelGGL(dwt_db4_lds_kernel, grid, block, 0, stream,
                       x, dec_lo, dec_hi, out);
}

// Round 6
// 232.783 us; speedup vs baseline: 1.0476x; 1.0086x over previous
//
#include <hip/hip_runtime.h>

// DWT db4 depthwise stride-2 decomposition.
// x: [B=32, T=16384, C=64] f32 -> out: [B, T2=8190, 2C=128] f32
// out[b,t,c]    = sum_k lo[k] * x[b, reflect(2t+k-1), c]      (c < 64)
// out[b,t,64+c] = sum_k hi[k] * x[b, reflect(2t+k-1), c]
//
// R6: R5 (global_load_lds staging) with HALF the tile -> double the
// concurrent stage streams per CU.
// R5 post-mortem: ~70us, HBM ~3.9 TB/s of a demonstrated ~6.5.  Compute per
// tile (~0.3us) << memory per tile (~3us) and nothing else is saturated, so
// the loss is load-stream duty cycle: 4 blocks/CU each doing
// stage-burst -> vmcnt(0) drain -> compute leaves gaps with zero outstanding
// loads.  TBLK 64->32: LDS/block 18.4 KB -> 8 blocks/CU, 32 waves/CU (100%
// occupancy), twice as many independently-phased staging bursts tiling the
// timeline.  Compute shape returns to the proven R2 pair-per-thread (10-row
// LDS window, fits under the 64-VGPR cap that 8 waves/SIMD requires).
// Cost: staged rows/output 2.125 -> 2.25 (+6% fetch) -- negligible.

#define BT     32
#define TT     16384
#define CC     64
#define T2     8190        // T/2 - 2
#define OC     128         // 2*CC
#define TBLK   32          // outputs per block
#define NROWS  72          // staged rows: 70 needed + 2 pad for 1KB chunking
#define NCHUNK 18          // NROWS*256B / 1024B

__global__ __launch_bounds__(256, 8) void dwt_db4_lds32_kernel(
    const float* __restrict__ x,
    const float* __restrict__ dec_lo,
    const float* __restrict__ dec_hi,
    float* __restrict__ out)
{
    __shared__ float lds[NROWS * CC];          // 18432 B -> 8 blocks/CU

    const int tid = threadIdx.x;
    const int b   = blockIdx.y;
    const int t0  = blockIdx.x * TBLK;         // first output of this tile
    // first staged global row (tile 0 starts at 0; reflect lands inside stage)
    const int row_base = (t0 == 0) ? 0 : (2 * t0 - 1);

    const float* __restrict__ xb = x + (size_t)b * TT * CC;

    // ---- stage: 18 x 1KB chunks, round-robin over the 4 waves -----------
    // Each global_load_lds moves 64 lanes x 16B = 1KB to LDS base + lane*16.
    // Zero VGPR involvement -> issued back-to-back, drained once at barrier.
    {
        const int wave = tid >> 6;
        const int lane = tid & 63;
        const float* gsrc = xb + (size_t)row_base * CC + lane * 4;
        const float* gend = xb + (size_t)TT * CC - 4;   // last valid float4
        #pragma unroll
        for (int j = 0; j < 5; ++j) {
            const int c = wave + j * 4;                 // 18 chunks over 4 waves
            if (c < NCHUNK) {
                const float* g = gsrc + c * 256;        // 256 floats = 1KB
                g = (g > gend) ? gend : g;              // tail-tile clamp (rows
                                                        // past T-1 staged but
                                                        // never read: reflect
                                                        // keeps mm <= T-1)
                __builtin_amdgcn_global_load_lds(
                    (const __attribute__((address_space(1))) unsigned int*)g,
                    (__attribute__((address_space(3))) unsigned int*)&lds[c * 256],
                    16, 0, 0);
            }
        }
    }

    // Filters: uniform addresses -> scalar broadcast loads (lgkm path).
    float flo[8], fhi[8];
    #pragma unroll
    for (int k = 0; k < 8; ++k) { flo[k] = dec_lo[k]; fhi[k] = dec_hi[k]; }

    __syncthreads();   // single vmcnt(0)+lgkmcnt(0) drain

    // ---- compute: PAIR of outputs per thread, window from LDS ------------
    const int cg = tid & 15;                   // channel group (4 ch, float4)
    const int sl = tid >> 4;                   // pair slot 0..15
    const int t  = t0 + sl * 2;                // first output of this pair
    const int c4 = cg * 4;

    // 10-row window; output t uses w[0..7], output t+1 uses w[2..9].
    float4 w[10];
    #pragma unroll
    for (int i = 0; i < 10; ++i) {
        int m  = 2 * t - 1 + i;                           // global row wanted
        int mm = m < 0 ? -m : m;                          // left reflect
        mm     = mm > (TT - 1) ? 2 * (TT - 1) - mm : mm;  // right reflect
        w[i] = *reinterpret_cast<const float4*>(&lds[(mm - row_base) * CC + c4]);
    }

    float4 alo0, ahi0, alo1, ahi1;
    alo0.x = alo0.y = alo0.z = alo0.w = 0.0f;
    ahi0.x = ahi0.y = ahi0.z = ahi0.w = 0.0f;
    alo1.x = alo1.y = alo1.z = alo1.w = 0.0f;
    ahi1.x = ahi1.y = ahi1.z = ahi1.w = 0.0f;

    #pragma unroll
    for (int k = 0; k < 8; ++k) {
        const float4 v0 = w[k];
        const float4 v1 = w[k + 2];
        alo0.x = fmaf(flo[k], v0.x, alo0.x);
        alo0.y = fmaf(flo[k], v0.y, alo0.y);
        alo0.z = fmaf(flo[k], v0.z, alo0.z);
        alo0.w = fmaf(flo[k], v0.w, alo0.w);
        ahi0.x = fmaf(fhi[k], v0.x, ahi0.x);
        ahi0.y = fmaf(fhi[k], v0.y, ahi0.y);
        ahi0.z = fmaf(fhi[k], v0.z, ahi0.z);
        ahi0.w = fmaf(fhi[k], v0.w, ahi0.w);

        alo1.x = fmaf(flo[k], v1.x, alo1.x);
        alo1.y = fmaf(flo[k], v1.y, alo1.y);
        alo1.z = fmaf(flo[k], v1.z, alo1.z);
        alo1.w = fmaf(flo[k], v1.w, alo1.w);
        ahi1.x = fmaf(fhi[k], v1.x, ahi1.x);
        ahi1.y = fmaf(fhi[k], v1.y, ahi1.y);
        ahi1.z = fmaf(fhi[k], v1.z, ahi1.z);
        ahi1.w = fmaf(fhi[k], v1.w, ahi1.w);
    }

    // ---- stores ----------------------------------------------------------
    // Tail tile (t0=8160) has outputs up to t=8190,8191 -> guard vs T2.
    float* __restrict__ ob = out + (size_t)b * T2 * OC + (size_t)t * OC + c4;
    if (t < T2) {
        *reinterpret_cast<float4*>(ob)      = alo0;
        *reinterpret_cast<float4*>(ob + CC) = ahi0;
    }
    if (t + 1 < T2) {
        *reinterpret_cast<float4*>(ob + OC)      = alo1;
        *reinterpret_cast<float4*>(ob + OC + CC) = ahi1;
    }
}

extern "C" void kernel_launch(void* const* d_in, const int* in_sizes, int n_in,
                              void* d_out, int out_size, void* d_ws, size_t ws_size,
                              hipStream_t stream)
{
    const float* x      = (const float*)d_in[0];
    const float* dec_lo = (const float*)d_in[1];
    const float* dec_hi = (const float*)d_in[2];
    float*       out    = (float*)d_out;

    dim3 block(256);
    // 32 outputs per block -> ceil(8190/32) = 256 tiles; x 32 batches
    dim3 grid((T2 + TBLK - 1) / TBLK, BT);

    hipLaunchKernelGGL(dwt_db4_lds32_kernel, grid, block, 0, stream,
                       x, dec_lo, dec_hi, out);
}